// Round 2
// baseline (337.936 us; speedup 1.0000x reference)
//
#include <hip/hip_runtime.h>
#include <math.h>

// GAT layer, N=8192, F_in=128, F_out=64, fp32.
// e[i][j] = leaky(f1[i]+f2[j]) is piecewise-separable => softmax(e)@h
// collapses to prefix sums of exp(f2)*h / exp(0.2 f2)*h ordered by f2.
// Bucket-histogram CDF (4096 buckets over [-12,12]) replaces the sort;
// measured absmax 9.8e-4 << 6.25e-3 threshold (R1).
//
// R2: fused 1-kernel scan (was 3 kernels; k2b had ~64 serialized global
// round-trips), K1 computes 4 rows/wave to amortize LDS reads of W.

constexpr int N    = 8192;
constexpr int FIN  = 128;
constexpr int FOUT = 64;
constexpr int B    = 4096;            // histogram buckets
constexpr float LO = -12.0f;
constexpr float SCALE = (float)B / 24.0f;
constexpr float NEG_SLOPE = 0.2f;

__device__ __forceinline__ int bucket_of(float x) {
    int b = (int)floorf((x - LO) * SCALE);
    return min(max(b, 0), B - 1);
}

// K1: h = X@W (4 rows per wave, W staged in LDS), f1/f2 via butterfly
// reduce, scatter exp(f2)*h and exp(0.2 f2)*h into bucket histograms.
__global__ __launch_bounds__(256) void k1_h_hist(
    const float* __restrict__ X, const float* __restrict__ W,
    const float* __restrict__ a,
    float* __restrict__ U, float* __restrict__ V,
    float* __restrict__ pu, float* __restrict__ pv,
    float* __restrict__ f1out)
{
    __shared__ float Wl[FIN * FOUT];
    __shared__ float a1l[FOUT], a2l[FOUT];
    int tid = threadIdx.x;
    for (int i = tid; i < FIN * FOUT; i += 256) Wl[i] = W[i];
    if (tid < FOUT) { a1l[tid] = a[tid]; a2l[tid] = a[FOUT + tid]; }
    __syncthreads();

    int wave = tid >> 6, lane = tid & 63;
    int r0 = (blockIdx.x * 4 + wave) * 4;           // 4 rows per wave

    const float4* x0 = (const float4*)(X + (size_t)(r0 + 0) * FIN);
    const float4* x1 = (const float4*)(X + (size_t)(r0 + 1) * FIN);
    const float4* x2 = (const float4*)(X + (size_t)(r0 + 2) * FIN);
    const float4* x3 = (const float4*)(X + (size_t)(r0 + 3) * FIN);

    float acc0 = 0.f, acc1 = 0.f, acc2 = 0.f, acc3 = 0.f;
#pragma unroll 4
    for (int k4 = 0; k4 < FIN / 4; ++k4) {
        float4 xa = x0[k4], xb = x1[k4], xc = x2[k4], xd = x3[k4];
        int k = k4 * 4;
        float w0 = Wl[(k + 0) * FOUT + lane];       // lane stride 64 -> 2-way bank alias, free
        float w1 = Wl[(k + 1) * FOUT + lane];
        float w2 = Wl[(k + 2) * FOUT + lane];
        float w3 = Wl[(k + 3) * FOUT + lane];
        acc0 += xa.x * w0 + xa.y * w1 + xa.z * w2 + xa.w * w3;
        acc1 += xb.x * w0 + xb.y * w1 + xb.z * w2 + xb.w * w3;
        acc2 += xc.x * w0 + xc.y * w1 + xc.z * w2 + xc.w * w3;
        acc3 += xd.x * w0 + xd.y * w1 + xd.z * w2 + xd.w * w3;
    }

    float a1 = a1l[lane], a2 = a2l[lane];
    float p10 = acc0 * a1, p20 = acc0 * a2;
    float p11 = acc1 * a1, p21 = acc1 * a2;
    float p12 = acc2 * a1, p22 = acc2 * a2;
    float p13 = acc3 * a1, p23 = acc3 * a2;
#pragma unroll
    for (int off = 32; off > 0; off >>= 1) {
        p10 += __shfl_xor(p10, off); p20 += __shfl_xor(p20, off);
        p11 += __shfl_xor(p11, off); p21 += __shfl_xor(p21, off);
        p12 += __shfl_xor(p12, off); p22 += __shfl_xor(p22, off);
        p13 += __shfl_xor(p13, off); p23 += __shfl_xor(p23, off);
    }
    if (lane == 0) {
        f1out[r0 + 0] = p10; f1out[r0 + 1] = p11;
        f1out[r0 + 2] = p12; f1out[r0 + 3] = p13;
    }

    // per-row histogram scatter
    {
        float e2 = expf(p20), e02 = expf(NEG_SLOPE * p20);
        int b = bucket_of(p20);
        atomicAdd(&U[(size_t)b * FOUT + lane], e2 * acc0);
        atomicAdd(&V[(size_t)b * FOUT + lane], e02 * acc0);
        if (lane == 0) { atomicAdd(&pu[b], e2); atomicAdd(&pv[b], e02); }
    }
    {
        float e2 = expf(p21), e02 = expf(NEG_SLOPE * p21);
        int b = bucket_of(p21);
        atomicAdd(&U[(size_t)b * FOUT + lane], e2 * acc1);
        atomicAdd(&V[(size_t)b * FOUT + lane], e02 * acc1);
        if (lane == 0) { atomicAdd(&pu[b], e2); atomicAdd(&pv[b], e02); }
    }
    {
        float e2 = expf(p22), e02 = expf(NEG_SLOPE * p22);
        int b = bucket_of(p22);
        atomicAdd(&U[(size_t)b * FOUT + lane], e2 * acc2);
        atomicAdd(&V[(size_t)b * FOUT + lane], e02 * acc2);
        if (lane == 0) { atomicAdd(&pu[b], e2); atomicAdd(&pv[b], e02); }
    }
    {
        float e2 = expf(p23), e02 = expf(NEG_SLOPE * p23);
        int b = bucket_of(p23);
        atomicAdd(&U[(size_t)b * FOUT + lane], e2 * acc3);
        atomicAdd(&V[(size_t)b * FOUT + lane], e02 * acc3);
        if (lane == 0) { atomicAdd(&pu[b], e2); atomicAdd(&pv[b], e02); }
    }
}

// K2 (fused): inclusive column scan over 4096 buckets, in place.
// blocks 0..15:  U, 4 columns each (float4)
// blocks 16..31: V, 4 columns each
// block 32: pu (4096 scalars), block 33: pv
__global__ __launch_bounds__(256) void k2_scan(
    float* __restrict__ U, float* __restrict__ V,
    float* __restrict__ pu, float* __restrict__ pv)
{
    int blk = blockIdx.x;
    int tid = threadIdx.x, lane = tid & 63, wid = tid >> 6;
    __shared__ float4 wsum4[4];
    __shared__ float  wsum1[4];

    if (blk < 32) {
        float* A = (blk < 16) ? U : V;
        float4* A4 = (float4*)A;                     // 16 float4 per bucket row
        int cg = blk & 15;                           // column group (4 cols)
        float4 vals[16];
        float4 s = make_float4(0.f, 0.f, 0.f, 0.f);
#pragma unroll
        for (int m = 0; m < 16; ++m) {
            vals[m] = A4[(size_t)(tid * 16 + m) * 16 + cg];
            s.x += vals[m].x; s.y += vals[m].y; s.z += vals[m].z; s.w += vals[m].w;
        }
        // wave-inclusive scan of per-thread sums (component-wise)
        float4 inc = s;
#pragma unroll
        for (int off = 1; off < 64; off <<= 1) {
            float tx = __shfl_up(inc.x, off);
            float ty = __shfl_up(inc.y, off);
            float tz = __shfl_up(inc.z, off);
            float tw = __shfl_up(inc.w, off);
            if (lane >= off) { inc.x += tx; inc.y += ty; inc.z += tz; inc.w += tw; }
        }
        if (lane == 63) wsum4[wid] = inc;
        __syncthreads();
        float4 run = make_float4(inc.x - s.x, inc.y - s.y, inc.z - s.z, inc.w - s.w);
        for (int w = 0; w < wid; ++w) {
            float4 t = wsum4[w];
            run.x += t.x; run.y += t.y; run.z += t.z; run.w += t.w;
        }
#pragma unroll
        for (int m = 0; m < 16; ++m) {
            run.x += vals[m].x; run.y += vals[m].y;
            run.z += vals[m].z; run.w += vals[m].w;
            A4[(size_t)(tid * 16 + m) * 16 + cg] = run;
        }
    } else {
        float* P = (blk == 32) ? pu : pv;
        float4* P4 = (float4*)P;
        float4 vals[4];
        float s = 0.f;
#pragma unroll
        for (int m = 0; m < 4; ++m) {
            vals[m] = P4[tid * 4 + m];
            s += vals[m].x + vals[m].y + vals[m].z + vals[m].w;
        }
        float inc = s;
#pragma unroll
        for (int off = 1; off < 64; off <<= 1) {
            float t = __shfl_up(inc, off);
            if (lane >= off) inc += t;
        }
        if (lane == 63) wsum1[wid] = inc;
        __syncthreads();
        float run = inc - s;
        for (int w = 0; w < wid; ++w) run += wsum1[w];
#pragma unroll
        for (int m = 0; m < 4; ++m) {
            float4 v = vals[m];
            float4 o;
            o.x = run + v.x;
            o.y = o.x + v.y;
            o.z = o.y + v.z;
            o.w = o.z + v.w;
            run = o.w;
            P4[tid * 4 + m] = o;
        }
    }
}

// K3: per row i, split sums at bucket(-f1[i]), combine two branches, ELU.
__global__ __launch_bounds__(256) void k3_combine(
    const float* __restrict__ f1a,
    const float* __restrict__ U, const float* __restrict__ V,
    const float* __restrict__ pu, const float* __restrict__ pv,
    float* __restrict__ out)
{
    int tid = threadIdx.x, lane = tid & 63, wave = tid >> 6;
    int i = blockIdx.x * 4 + wave;
    float f1 = f1a[i];
    int b = bucket_of(-f1);
    float A  = expf(f1);
    float Bv = expf(NEG_SLOPE * f1);

    float Utot = U[((size_t)B - 1) * FOUT + lane];
    float putot = pu[B - 1];
    float Upre = 0.f, Vpre = 0.f, pupre = 0.f, pvpre = 0.f;
    if (b > 0) {
        Upre = U[((size_t)b - 1) * FOUT + lane];
        Vpre = V[((size_t)b - 1) * FOUT + lane];
        pupre = pu[b - 1];
        pvpre = pv[b - 1];
    }
    float num = A * (Utot - Upre) + Bv * Vpre;
    float den = A * (putot - pupre) + Bv * pvpre;
    float r = num / den;
    out[(size_t)i * FOUT + lane] = r > 0.f ? r : expm1f(r);
}

extern "C" void kernel_launch(void* const* d_in, const int* in_sizes, int n_in,
                              void* d_out, int out_size, void* d_ws, size_t ws_size,
                              hipStream_t stream)
{
    const float* X = (const float*)d_in[0];
    // d_in[1] = adj_matrix (all-ones, unused by the reference) — never touched.
    const float* W = (const float*)d_in[2];
    const float* a = (const float*)d_in[3];
    float* out = (float*)d_out;

    float* ws = (float*)d_ws;
    float* U  = ws;                          // B*FOUT
    float* V  = U + (size_t)B * FOUT;        // B*FOUT
    float* pu = V + (size_t)B * FOUT;        // B
    float* pv = pu + B;                      // B
    float* f1 = pv + B;                      // N

    // zero the histogram region (U,V,pu,pv are contiguous)
    hipMemsetAsync(U, 0, ((size_t)B * FOUT * 2 + 2 * (size_t)B) * sizeof(float), stream);

    k1_h_hist<<<N / 16, 256, 0, stream>>>(X, W, a, U, V, pu, pv, f1);
    k2_scan<<<34, 256, 0, stream>>>(U, V, pu, pv);
    k3_combine<<<N / 4, 256, 0, stream>>>(f1, U, V, pu, pv, out);
}